// Round 1
// baseline (556.011 us; speedup 1.0000x reference)
//
#include <hip/hip_runtime.h>
#include <cstdint>
#include <cstddef>

#define NB 8
#define NN 65536
#define NC 16
#define GG 64
#define GG3 (GG*GG*GG)
#define EPSC 1e-3f

// ---------------------------------------------------------------------------
// Stage 1: scatter valid rows into a dense (B, G^3) index map (pre-memset -1)
// ---------------------------------------------------------------------------
__global__ __launch_bounds__(256) void build_map_kernel(
    const int* __restrict__ xyz, const int* __restrict__ nvv,
    int* __restrict__ idx_map)
{
    int b = blockIdx.y;
    int n = blockIdx.x * 256 + threadIdx.x;
    if (n < nvv[b]) {
        const int* cp = xyz + ((size_t)b * NN + n) * 3;
        int lin = cp[0] * (GG * GG) + cp[1] * GG + cp[2];
        idx_map[(size_t)b * GG3 + lin] = n;
    }
}

// ---------------------------------------------------------------------------
// Stage 2: fused sparse conv + ones-conv normalizer + BN partial stats.
// One thread per voxel; 16 accumulators; weights are wave-uniform (s_loads).
// Writes t = conv(x)/(1+|normc|) for valid rows; block-reduces sum/sumsq.
// ---------------------------------------------------------------------------
__global__ __launch_bounds__(256) void conv_kernel(
    const float* __restrict__ feats,     // (B,N,16)
    const int*   __restrict__ xyz,       // (B,N,3)
    const int*   __restrict__ nvv,       // (B,)
    const int*   __restrict__ idx_map,   // (B,G3)
    const float* __restrict__ w,         // (27,16,16)
    const float* __restrict__ nw,        // (27,)
    float*       __restrict__ outbuf,    // (B,N,16)
    float*       __restrict__ partials)  // (gridDim.y*gridDim.x, 32)
{
    int b = blockIdx.y;
    int n = blockIdx.x * 256 + threadIdx.x;
    int nv = nvv[b];

    float t[16];
    #pragma unroll
    for (int o = 0; o < 16; o++) t[o] = 0.f;

    if (n < nv) {
        const int* cp = xyz + ((size_t)b * NN + n) * 3;
        int x = cp[0], y = cp[1], z = cp[2];
        const int* imap = idx_map + (size_t)b * GG3;
        const float* fb = feats + (size_t)b * NN * 16;

        float acc[16];
        #pragma unroll
        for (int o = 0; o < 16; o++) acc[o] = 0.f;
        float normc = 0.f;

        #pragma unroll 1
        for (int off = 0; off < 27; off++) {
            int dx = off / 9 - 1, dy = (off / 3) % 3 - 1, dz = off % 3 - 1;
            int nx = x + dx, ny = y + dy, nz = z + dz;
            int j = -1;
            if ((unsigned)nx < GG && (unsigned)ny < GG && (unsigned)nz < GG)
                j = imap[nx * (GG * GG) + ny * GG + nz];
            if (j >= 0) {
                normc += nw[off];
                const float4* fp = (const float4*)(fb + (size_t)j * 16);
                float4 f0 = fp[0], f1 = fp[1], f2 = fp[2], f3 = fp[3];
                float f[16] = {f0.x, f0.y, f0.z, f0.w, f1.x, f1.y, f1.z, f1.w,
                               f2.x, f2.y, f2.z, f2.w, f3.x, f3.y, f3.z, f3.w};
                const float* wp = w + off * 256;   // wave-uniform -> s_load
                #pragma unroll
                for (int c = 0; c < 16; c++) {
                    #pragma unroll
                    for (int o = 0; o < 16; o++)
                        acc[o] = fmaf(f[c], wp[c * 16 + o], acc[o]);
                }
            }
        }

        float r = 1.f / (1.f + fabsf(normc));
        #pragma unroll
        for (int o = 0; o < 16; o++) t[o] = acc[o] * r;

        float4* op = (float4*)(outbuf + ((size_t)b * NN + n) * 16);
        op[0] = make_float4(t[0],  t[1],  t[2],  t[3]);
        op[1] = make_float4(t[4],  t[5],  t[6],  t[7]);
        op[2] = make_float4(t[8],  t[9],  t[10], t[11]);
        op[3] = make_float4(t[12], t[13], t[14], t[15]);
    }

    // --- BN partial stats: 32 values (sum[0:16], sumsq[16:32]) ---
    __shared__ float red[4][32];
    int lane = threadIdx.x & 63;
    int wv = threadIdx.x >> 6;
    #pragma unroll
    for (int s = 0; s < 32; s++) {
        float v = (s < 16) ? t[s] : t[s - 16] * t[s - 16];
        v += __shfl_down(v, 32, 64);
        v += __shfl_down(v, 16, 64);
        v += __shfl_down(v, 8, 64);
        v += __shfl_down(v, 4, 64);
        v += __shfl_down(v, 2, 64);
        v += __shfl_down(v, 1, 64);
        if (lane == 0) red[wv][s] = v;
    }
    __syncthreads();
    if (threadIdx.x < 32) {
        float v = red[0][threadIdx.x] + red[1][threadIdx.x] +
                  red[2][threadIdx.x] + red[3][threadIdx.x];
        partials[((size_t)blockIdx.y * gridDim.x + blockIdx.x) * 32 + threadIdx.x] = v;
    }
}

// ---------------------------------------------------------------------------
// Stage 3: reduce partials -> per-channel scale/bias (single block)
// ---------------------------------------------------------------------------
__global__ __launch_bounds__(256) void finalize_kernel(
    const float* __restrict__ partials, int nparts,
    const int*   __restrict__ nvv,
    const float* __restrict__ gamma, const float* __restrict__ beta,
    float*       __restrict__ sb)     // sb[0:16]=scale, sb[16:32]=bias
{
    __shared__ float red[8][32];
    __shared__ float tot[32];
    int s = threadIdx.x & 31;
    int ch = threadIdx.x >> 5;
    float v = 0.f;
    for (int r = ch; r < nparts; r += 8)
        v += partials[(size_t)r * 32 + s];
    red[ch][s] = v;
    __syncthreads();
    if (threadIdx.x < 32) {
        float x = 0.f;
        #pragma unroll
        for (int k = 0; k < 8; k++) x += red[k][threadIdx.x];
        tot[threadIdx.x] = x;
    }
    __syncthreads();
    if (threadIdx.x < 16) {
        float cnt = 0.f;
        #pragma unroll
        for (int b = 0; b < NB; b++) cnt += (float)nvv[b];
        float mean = tot[threadIdx.x] / cnt;
        float var  = tot[16 + threadIdx.x] / cnt - mean * mean;
        var = fmaxf(var, 0.f);
        float sc = gamma[threadIdx.x] * rsqrtf(var + EPSC);
        sb[threadIdx.x]      = sc;
        sb[16 + threadIdx.x] = beta[threadIdx.x] - mean * sc;
    }
}

// ---------------------------------------------------------------------------
// Stage 4: y = relu(x*scale + bias) * valid_mask  (writes ALL rows)
// ---------------------------------------------------------------------------
__global__ __launch_bounds__(256) void bnrelu_kernel(
    const float* __restrict__ in, const float* __restrict__ sb,
    const int* __restrict__ nvv, float* __restrict__ out)
{
    size_t i = (size_t)blockIdx.x * 256 + threadIdx.x;   // one float4
    int row = (int)(i >> 2);          // b*N + n
    int b = row >> 16;                // N == 65536
    int n = row & (NN - 1);
    int o = ((int)i & 3) * 4;
    float4 x = ((const float4*)in)[i];
    float4 y;
    y.x = fmaxf(fmaf(x.x, sb[o + 0], sb[16 + o + 0]), 0.f);
    y.y = fmaxf(fmaf(x.y, sb[o + 1], sb[16 + o + 1]), 0.f);
    y.z = fmaxf(fmaf(x.z, sb[o + 2], sb[16 + o + 2]), 0.f);
    y.w = fmaxf(fmaf(x.w, sb[o + 3], sb[16 + o + 3]), 0.f);
    if (n >= nvv[b]) { y.x = 0.f; y.y = 0.f; y.z = 0.f; y.w = 0.f; }
    ((float4*)out)[i] = y;
}

// ---------------------------------------------------------------------------
extern "C" void kernel_launch(void* const* d_in, const int* in_sizes, int n_in,
                              void* d_out, int out_size, void* d_ws, size_t ws_size,
                              hipStream_t stream)
{
    const float* feats  = (const float*)d_in[0];
    const int*   xyz    = (const int*)d_in[1];
    const int*   nvv    = (const int*)d_in[2];
    const float* w0     = (const float*)d_in[3];
    const float* w1     = (const float*)d_in[4];
    const float* nw0    = (const float*)d_in[5];
    const float* nw1    = (const float*)d_in[6];
    const float* gamma0 = (const float*)d_in[7];
    const float* beta0  = (const float*)d_in[8];
    const float* gamma1 = (const float*)d_in[9];
    const float* beta1  = (const float*)d_in[10];
    float* out = (float*)d_out;

    char* ws = (char*)d_ws;
    int*   idx_map  = (int*)ws;            ws += (size_t)NB * GG3 * 4;     // 8 MB
    float* bufA     = (float*)ws;          ws += (size_t)NB * NN * 16 * 4; // 32 MB
    float* bufB     = (float*)ws;          ws += (size_t)NB * NN * 16 * 4; // 32 MB
    float* partials = (float*)ws;          ws += (size_t)2048 * 32 * 4;    // 256 KB
    float* sb       = (float*)ws;          ws += 32 * 4;

    hipMemsetAsync(idx_map, 0xFF, (size_t)NB * GG3 * 4, stream);

    dim3 gridBN(NN / 256, NB);   // 256 x 8 blocks
    build_map_kernel<<<gridBN, 256, 0, stream>>>(xyz, nvv, idx_map);

    // Layer 1
    conv_kernel<<<gridBN, 256, 0, stream>>>(feats, xyz, nvv, idx_map, w0, nw0, bufA, partials);
    finalize_kernel<<<1, 256, 0, stream>>>(partials, NN / 256 * NB, nvv, gamma0, beta0, sb);
    bnrelu_kernel<<<(size_t)NB * NN * 16 / 4 / 256, 256, 0, stream>>>(bufA, sb, nvv, bufA);

    // Layer 2
    conv_kernel<<<gridBN, 256, 0, stream>>>(bufA, xyz, nvv, idx_map, w1, nw1, bufB, partials);
    finalize_kernel<<<1, 256, 0, stream>>>(partials, NN / 256 * NB, nvv, gamma1, beta1, sb);
    bnrelu_kernel<<<(size_t)NB * NN * 16 / 4 / 256, 256, 0, stream>>>(bufB, sb, nvv, out);
}